// Round 1
// baseline (146.709 us; speedup 1.0000x reference)
//
#include <hip/hip_runtime.h>
#include <hip/hip_bf16.h>

// Conv 3x3, C_IN=128, C_OUT=256, H=W=256, pad=1, stride=1, batch=1.
// Implicit GEMM: D[m=co][n=h*W+w] = sum_{khw,ci} Wr[khw][co][ci] * Xb[h+kh][w+kw][ci]
//   M=256, N=65536, K=1152 -> 38.65 GFLOP, bf16 MFMA 16x16x32.

typedef short bf16x8 __attribute__((ext_vector_type(8)));    // 8 bf16 = 4 VGPRs
typedef float f32x4 __attribute__((ext_vector_type(4)));
typedef unsigned short u16x4 __attribute__((ext_vector_type(4)));
typedef unsigned short u16x8 __attribute__((ext_vector_type(8)));

#define CIN   128
#define COUT  256
#define HH    256
#define WW    256
#define HP    258                 // padded
#define ROWP  (HP * CIN)          // padded row stride in elems = 33024

static __device__ __forceinline__ unsigned short f2bf(float v) {
    __hip_bfloat16 b = __float2bfloat16(v);
    return *reinterpret_cast<unsigned short*>(&b);
}

// ---------------- pre-pass 1: x NCHW fp32 -> padded NHWC bf16 (interior) -------------
// grid: 256 h * 4 w-tiles = 1024 blocks, 256 threads
__global__ __launch_bounds__(256) void xpose_kernel(const float* __restrict__ x,
                                                    unsigned short* __restrict__ xb) {
    int bid = blockIdx.x;
    int h  = bid >> 2;
    int w0 = (bid & 3) * 64;
    __shared__ unsigned short tile[CIN * 72];   // [ci][w], w padded 64->72
    int t = threadIdx.x;

    // phase 1: coalesced read along w (float4), write bf16x4 to LDS [ci][w]
    int wq = t & 15;          // 16 * float4 = 64 w
    int cib = t >> 4;         // 16 ci per pass
    for (int c0 = 0; c0 < CIN; c0 += 16) {
        int ci = c0 + cib;
        float4 v = *(const float4*)(x + ci * (HH * WW) + h * WW + w0 + wq * 4);
        u16x4 p;
        p.x = f2bf(v.x); p.y = f2bf(v.y); p.z = f2bf(v.z); p.w = f2bf(v.w);
        *(u16x4*)(&tile[ci * 72 + wq * 4]) = p;
    }
    __syncthreads();

    // phase 2: write NHWC, contiguous 16 KB per block
    for (int it = 0; it < 4; ++it) {
        int idx = it * 256 + t;       // 0..1023
        int w  = idx >> 4;            // 0..63
        int c8 = idx & 15;            // 0..15 (8 ci each)
        u16x8 o;
        #pragma unroll
        for (int j = 0; j < 8; ++j)
            o[j] = tile[(c8 * 8 + j) * 72 + w];
        int dst = ((h + 1) * HP + (w0 + w + 1)) * CIN + c8 * 8;
        *(u16x8*)(&xb[dst]) = o;
    }
}

// ---------------- pre-pass 1b: zero the padding border of xb -------------------------
// tasks (vec8): rows hp=0,257: 2*4128 = 8256 ; cols wp=0,257 (hp 1..256): 8192. total 16448
__global__ __launch_bounds__(256) void zero_edges_kernel(unsigned short* __restrict__ xb) {
    int i = blockIdx.x * 256 + threadIdx.x;
    if (i >= 16448) return;
    u16x8 z = {0, 0, 0, 0, 0, 0, 0, 0};
    int off;
    if (i < 8256) {
        int r   = (i >= 4128) ? 1 : 0;
        int rem = i - r * 4128;
        off = (r * 257) * ROWP + rem * 8;
    } else {
        int j   = i - 8256;           // 0..8191
        int col = j >> 12;            // 0 or 1
        int rem = j & 4095;
        int hp  = (rem >> 4) + 1;     // 1..256
        int c8  = rem & 15;
        off = hp * ROWP + (col * 257) * CIN + c8 * 8;
    }
    *(u16x8*)(&xb[off]) = z;
}

// ---------------- pre-pass 2: weight [co][ci][kh][kw] fp32 -> Wr[khw][co][ci] bf16 ---
__global__ __launch_bounds__(256) void wreorder_kernel(const float* __restrict__ w,
                                                       unsigned short* __restrict__ wr) {
    int i = blockIdx.x * 256 + threadIdx.x;   // 294912 total
    int khw = i >> 15;
    int rem = i & 32767;
    int co  = rem >> 7;
    int ci  = rem & 127;
    wr[i] = f2bf(w[co * (CIN * 9) + ci * 9 + khw]);
}

// ---------------- main: implicit-GEMM MFMA conv --------------------------------------
// block tile: 128 co x 128 spatial (one h row, half of w). 4 waves (2x2), each 64x64.
// K-loop: 9 khw x 2 ci-chunks of 64. LDS tiles [128][64] bf16, rows padded to 72 elems.
#define LROW 72

__global__ __launch_bounds__(256) void conv_mfma_kernel(const unsigned short* __restrict__ xb,
                                                        const unsigned short* __restrict__ wr,
                                                        const float* __restrict__ bias,
                                                        float* __restrict__ out) {
    __shared__ unsigned short As[128 * LROW];   // [co][k]      18432 B
    __shared__ unsigned short Bs[128 * LROW];   // [spatial][k] 18432 B

    int bid  = blockIdx.x;        // 1024
    int co_t = bid & 1;
    int wh   = (bid >> 1) & 1;
    int h    = bid >> 2;          // 0..255
    int co0  = co_t * 128;
    int p0   = h * WW + wh * 128;

    int t    = threadIdx.x;
    int wave = t >> 6;
    int lane = t & 63;
    int wm   = wave >> 1;         // co half (0/1)
    int wn   = wave & 1;          // spatial half (0/1)
    int quad = lane >> 4;
    int l16  = lane & 15;

    f32x4 acc[4][4];
    #pragma unroll
    for (int mi = 0; mi < 4; ++mi)
        #pragma unroll
        for (int ni = 0; ni < 4; ++ni)
            acc[mi][ni] = (f32x4){0.f, 0.f, 0.f, 0.f};

    // staging mapping: 1024 segs of 16B per tile; seg = it*256+t; r=seg>>3; s=seg&7
    for (int kh = 0; kh < 3; ++kh) {
        for (int kw = 0; kw < 3; ++kw) {
            int khw = kh * 3 + kw;
            const unsigned short* xsrc = xb + ((h + kh) * HP + wh * 128 + kw) * CIN;
            const unsigned short* wsrc = wr + khw * (COUT * CIN) + co0 * CIN;
            for (int cc = 0; cc < 2; ++cc) {
                int kofs = cc * 64;
                __syncthreads();
                #pragma unroll
                for (int it = 0; it < 4; ++it) {
                    int seg = it * 256 + t;
                    int r = seg >> 3;
                    int s = seg & 7;
                    int ge = kofs + s * 8;
                    float4 av = *(const float4*)(wsrc + r * CIN + ge);
                    float4 bv = *(const float4*)(xsrc + r * CIN + ge);
                    *(float4*)(&As[r * LROW + s * 8]) = av;
                    *(float4*)(&Bs[r * LROW + s * 8]) = bv;
                }
                __syncthreads();
                #pragma unroll
                for (int kk = 0; kk < 2; ++kk) {
                    bf16x8 af[4], bfr[4];
                    #pragma unroll
                    for (int mi = 0; mi < 4; ++mi)
                        af[mi] = *(bf16x8*)(&As[(wm * 64 + mi * 16 + l16) * LROW + kk * 32 + quad * 8]);
                    #pragma unroll
                    for (int ni = 0; ni < 4; ++ni)
                        bfr[ni] = *(bf16x8*)(&Bs[(wn * 64 + ni * 16 + l16) * LROW + kk * 32 + quad * 8]);
                    #pragma unroll
                    for (int mi = 0; mi < 4; ++mi)
                        #pragma unroll
                        for (int ni = 0; ni < 4; ++ni)
                            acc[mi][ni] = __builtin_amdgcn_mfma_f32_16x16x32_bf16(
                                af[mi], bfr[ni], acc[mi][ni], 0, 0, 0);
                }
            }
        }
    }

    // epilogue: C/D layout col(spatial)=lane&15, row(co)=quad*4+reg
    #pragma unroll
    for (int mi = 0; mi < 4; ++mi) {
        #pragma unroll
        for (int r = 0; r < 4; ++r) {
            int co = co0 + wm * 64 + mi * 16 + quad * 4 + r;
            float b = bias[co];
            float* orow = out + co * (HH * WW) + p0 + wn * 64 + l16;
            #pragma unroll
            for (int ni = 0; ni < 4; ++ni)
                orow[ni * 16] = acc[mi][ni][r] + b;
        }
    }
}

extern "C" void kernel_launch(void* const* d_in, const int* in_sizes, int n_in,
                              void* d_out, int out_size, void* d_ws, size_t ws_size,
                              hipStream_t stream) {
    const float* x    = (const float*)d_in[0];   // [1,128,256,256]
    const float* w    = (const float*)d_in[1];   // [256,128,3,3]
    const float* bias = (const float*)d_in[2];   // [256]
    float* out        = (float*)d_out;           // [1,256,256,256]

    unsigned short* xb = (unsigned short*)d_ws;              // 258*258*128 bf16 = 17,040,384 B
    unsigned short* wr = xb + (size_t)HP * HP * CIN;         // 9*256*128 bf16  =    589,824 B

    xpose_kernel<<<dim3(1024), dim3(256), 0, stream>>>(x, xb);
    zero_edges_kernel<<<dim3(65), dim3(256), 0, stream>>>(xb);
    wreorder_kernel<<<dim3(1152), dim3(256), 0, stream>>>(w, wr);
    conv_mfma_kernel<<<dim3(1024), dim3(256), 0, stream>>>(xb, wr, bias, out);
}

// Round 2
// 143.414 us; speedup vs baseline: 1.0230x; 1.0230x over previous
//
#include <hip/hip_runtime.h>
#include <hip/hip_bf16.h>

// Conv 3x3, C_IN=128, C_OUT=256, H=W=256, pad=1, stride=1, batch=1.
// Implicit GEMM: D[m=co][n=h*W+w] = sum_{khw,ci} Wr[khw][co][ci] * Xb[h+kh][w+kw][ci]
//   M=256, N=65536, K=1152 -> 38.65 GFLOP, bf16 MFMA 16x16x32.
// R2: conv staging via global_load_lds(16B) + XOR-swizzled unpadded LDS;
//     xpose phase-2 w-major lanes (kills 16-way bank conflict); wreorder coalesced.

typedef short bf16x8 __attribute__((ext_vector_type(8)));    // 8 bf16 = 4 VGPRs
typedef float f32x4 __attribute__((ext_vector_type(4)));
typedef unsigned short u16x4 __attribute__((ext_vector_type(4)));
typedef unsigned short u16x8 __attribute__((ext_vector_type(8)));

#define CIN   128
#define COUT  256
#define HH    256
#define WW    256
#define HP    258                 // padded
#define ROWP  (HP * CIN)          // padded row stride in elems = 33024

static __device__ __forceinline__ unsigned short f2bf(float v) {
    __hip_bfloat16 b = __float2bfloat16(v);
    return *reinterpret_cast<unsigned short*>(&b);
}

static __device__ __forceinline__ void gload_lds16(const unsigned short* g, unsigned short* l) {
    __builtin_amdgcn_global_load_lds(
        (const __attribute__((address_space(1))) unsigned int*)g,
        (__attribute__((address_space(3))) unsigned int*)l, 16, 0, 0);
}

// ---------------- pre-pass 1: x NCHW fp32 -> padded NHWC bf16 (interior) -------------
// grid: 256 h * 4 w-tiles = 1024 blocks, 256 threads
__global__ __launch_bounds__(256) void xpose_kernel(const float* __restrict__ x,
                                                    unsigned short* __restrict__ xb) {
    int bid = blockIdx.x;
    int h  = bid >> 2;
    int w0 = (bid & 3) * 64;
    __shared__ unsigned short tile[CIN * 72];   // [ci][w], w padded 64->72
    int t = threadIdx.x;

    // phase 1: coalesced read along w (float4), write bf16x4 to LDS [ci][w]
    int wq = t & 15;          // 16 * float4 = 64 w
    int cib = t >> 4;         // 16 ci per pass
    for (int c0 = 0; c0 < CIN; c0 += 16) {
        int ci = c0 + cib;
        float4 v = *(const float4*)(x + ci * (HH * WW) + h * WW + w0 + wq * 4);
        u16x4 p;
        p.x = f2bf(v.x); p.y = f2bf(v.y); p.z = f2bf(v.z); p.w = f2bf(v.w);
        *(u16x4*)(&tile[ci * 72 + wq * 4]) = p;
    }
    __syncthreads();

    // phase 2: w-major lane mapping -> LDS reads stride 2B across lanes (2-way, free).
    // Stores: 16B per lane at 256B stride; full lines covered by the block -> L2 merges.
    for (int it = 0; it < 4; ++it) {
        int idx = it * 256 + t;       // 0..1023
        int w  = idx & 63;            // varies within wave
        int c8 = idx >> 6;            // 0..15, wave-uniform
        u16x8 o;
        #pragma unroll
        for (int j = 0; j < 8; ++j)
            o[j] = tile[(c8 * 8 + j) * 72 + w];
        int dst = ((h + 1) * HP + (w0 + w + 1)) * CIN + c8 * 8;
        *(u16x8*)(&xb[dst]) = o;
    }
}

// ---------------- pre-pass 1b: zero the padding border of xb -------------------------
__global__ __launch_bounds__(256) void zero_edges_kernel(unsigned short* __restrict__ xb) {
    int i = blockIdx.x * 256 + threadIdx.x;
    if (i >= 16448) return;
    u16x8 z = {0, 0, 0, 0, 0, 0, 0, 0};
    int off;
    if (i < 8256) {
        int r   = (i >= 4128) ? 1 : 0;
        int rem = i - r * 4128;
        off = (r * 257) * ROWP + rem * 8;
    } else {
        int j   = i - 8256;           // 0..8191
        int col = j >> 12;            // 0 or 1
        int rem = j & 4095;
        int hp  = (rem >> 4) + 1;     // 1..256
        int c8  = rem & 15;
        off = hp * ROWP + (col * 257) * CIN + c8 * 8;
    }
    *(u16x8*)(&xb[off]) = z;
}

// ---------------- pre-pass 2: weight [co][ci][kh][kw] fp32 -> Wr[khw][co][ci] bf16 ---
// one thread per (co,ci): reads 9 consecutive floats (wave covers 2304B contiguous),
// writes one coalesced u16 per khw plane.
__global__ __launch_bounds__(256) void wreorder_kernel(const float* __restrict__ w,
                                                       unsigned short* __restrict__ wr) {
    int p = blockIdx.x * 256 + threadIdx.x;   // 32768 = 256co * 128ci
    const float* src = w + p * 9;
    #pragma unroll
    for (int khw = 0; khw < 9; ++khw)
        wr[khw * (COUT * CIN) + p] = f2bf(src[khw]);
}

// ---------------- main: implicit-GEMM MFMA conv --------------------------------------
// block tile: 128 co x 128 spatial (one h row, half of w). 4 waves (2x2), each 64x64.
// K-loop: 9 khw x 2 ci-chunks of 64. LDS tiles [128][64] bf16 UNPADDED (global_load_lds
// constraint), bank conflicts broken by XOR swizzle: 16B chunk c of row r lives at
// slot c ^ (r&7). 32 KB LDS -> 5 blocks/CU.
__global__ __launch_bounds__(256) void conv_mfma_kernel(const unsigned short* __restrict__ xb,
                                                        const unsigned short* __restrict__ wr,
                                                        const float* __restrict__ bias,
                                                        float* __restrict__ out) {
    __shared__ unsigned short As[128 * 64];   // [co][k] swizzled, 16384 B
    __shared__ unsigned short Bs[128 * 64];   // [spatial][k] swizzled, 16384 B

    int bid  = blockIdx.x;        // 1024
    int co_t = bid & 1;
    int wh   = (bid >> 1) & 1;
    int h    = bid >> 2;          // 0..255
    int co0  = co_t * 128;
    int p0   = h * WW + wh * 128;

    int t    = threadIdx.x;
    int wave = t >> 6;
    int lane = t & 63;
    int wm   = wave >> 1;         // co half (0/1)
    int wn   = wave & 1;          // spatial half (0/1)
    int quad = lane >> 4;
    int l16  = lane & 15;
    int sw   = l16 & 7;           // fragment-read swizzle (= row&7)

    // staging decomposition: lane -> (local row lr, slot s); source chunk c = s ^ lr
    int lr = lane >> 3;           // 0..7
    int s  = lane & 7;
    int cs = (s ^ lr) * 8;        // source k-offset (elems) for this lane's 16B

    f32x4 acc[4][4];
    #pragma unroll
    for (int mi = 0; mi < 4; ++mi)
        #pragma unroll
        for (int ni = 0; ni < 4; ++ni)
            acc[mi][ni] = (f32x4){0.f, 0.f, 0.f, 0.f};

    for (int kh = 0; kh < 3; ++kh) {
        for (int kw = 0; kw < 3; ++kw) {
            int khw = kh * 3 + kw;
            const unsigned short* xsrc = xb + ((h + kh) * HP + wh * 128 + kw) * CIN;
            const unsigned short* wsrc = wr + khw * (COUT * CIN) + co0 * CIN;
            for (int cc = 0; cc < 2; ++cc) {
                int kofs = cc * 64;
                __syncthreads();
                #pragma unroll
                for (int it = 0; it < 4; ++it) {
                    int cid = wave * 4 + it;          // 0..15: 8-row chunk id
                    int r   = cid * 8 + lr;           // tile row this lane feeds
                    int ge  = kofs + cs;              // swizzled source k-offset
                    gload_lds16(wsrc + r * CIN + ge, &As[cid * 512]);
                    gload_lds16(xsrc + r * CIN + ge, &Bs[cid * 512]);
                }
                __syncthreads();
                #pragma unroll
                for (int kk = 0; kk < 2; ++kk) {
                    bf16x8 af[4], bfr[4];
                    #pragma unroll
                    for (int mi = 0; mi < 4; ++mi) {
                        int row = wm * 64 + mi * 16 + l16;
                        af[mi] = *(bf16x8*)(&As[row * 64 + ((kk * 4 + quad) ^ sw) * 8]);
                    }
                    #pragma unroll
                    for (int ni = 0; ni < 4; ++ni) {
                        int row = wn * 64 + ni * 16 + l16;
                        bfr[ni] = *(bf16x8*)(&Bs[row * 64 + ((kk * 4 + quad) ^ sw) * 8]);
                    }
                    #pragma unroll
                    for (int mi = 0; mi < 4; ++mi)
                        #pragma unroll
                        for (int ni = 0; ni < 4; ++ni)
                            acc[mi][ni] = __builtin_amdgcn_mfma_f32_16x16x32_bf16(
                                af[mi], bfr[ni], acc[mi][ni], 0, 0, 0);
                }
            }
        }
    }

    // epilogue: C/D layout col(spatial)=lane&15, row(co)=quad*4+reg
    #pragma unroll
    for (int mi = 0; mi < 4; ++mi) {
        #pragma unroll
        for (int r = 0; r < 4; ++r) {
            int co = co0 + wm * 64 + mi * 16 + quad * 4 + r;
            float b = bias[co];
            float* orow = out + co * (HH * WW) + p0 + wn * 64 + l16;
            #pragma unroll
            for (int ni = 0; ni < 4; ++ni)
                orow[ni * 16] = acc[mi][ni][r] + b;
        }
    }
}

extern "C" void kernel_launch(void* const* d_in, const int* in_sizes, int n_in,
                              void* d_out, int out_size, void* d_ws, size_t ws_size,
                              hipStream_t stream) {
    const float* x    = (const float*)d_in[0];   // [1,128,256,256]
    const float* w    = (const float*)d_in[1];   // [256,128,3,3]
    const float* bias = (const float*)d_in[2];   // [256]
    float* out        = (float*)d_out;           // [1,256,256,256]

    unsigned short* xb = (unsigned short*)d_ws;              // 258*258*128 bf16 = 17,040,384 B
    unsigned short* wr = xb + (size_t)HP * HP * CIN;         // 9*256*128 bf16  =    589,824 B

    xpose_kernel<<<dim3(1024), dim3(256), 0, stream>>>(x, xb);
    zero_edges_kernel<<<dim3(65), dim3(256), 0, stream>>>(xb);
    wreorder_kernel<<<dim3(128), dim3(256), 0, stream>>>(w, wr);
    conv_mfma_kernel<<<dim3(1024), dim3(256), 0, stream>>>(xb, wr, bias, out);
}